// Round 7
// baseline (17.384 us; speedup 1.0000x reference)
//
#include <hip/hip_runtime.h>

#define BB 8
#define SS 4096
#define DD 1024
#define TEMP 0.1f
#define PADV -100.0f
#define EPSV 1e-8f

typedef __attribute__((address_space(1))) const void GV;
typedef __attribute__((address_space(3))) void LV;

// One block (1024 threads) per batch. Scan labels -> compacted positions in
// LDS, write label outputs + all pads for BOTH chunks, then emit pair
// descriptors desc[b][j] = (pos_j, pos_{(j+1)%c}) for j<c, (-1,-1) otherwise.
__global__ __launch_bounds__(1024) void compact_kernel(const int* __restrict__ labels,
                                                       int2* __restrict__ desc,
                                                       float* __restrict__ out_cos,
                                                       float* __restrict__ out_lab) {
    int b = blockIdx.x;
    int t = threadIdx.x;
    int lane = t & 63, wave = t >> 6;

    __shared__ int pos[SS];
    __shared__ int wsum[16];

    int4 v = ((const int4*)(labels + b * SS))[t];
    int vals[4] = {v.x, v.y, v.z, v.w};
    int mycnt = (vals[0] != -100) + (vals[1] != -100) + (vals[2] != -100) + (vals[3] != -100);

    int scan = mycnt;
#pragma unroll
    for (int off = 1; off < 64; off <<= 1) {
        int n = __shfl_up(scan, off, 64);
        if (lane >= off) scan += n;
    }
    if (lane == 63) wsum[wave] = scan;
    __syncthreads();

    int wbase = 0, c = 0;
#pragma unroll
    for (int w = 0; w < 16; ++w) {
        int s = wsum[w];
        wbase += (w < wave) ? s : 0;
        c += s;
    }
    int o = wbase + scan - mycnt;

#pragma unroll
    for (int i = 0; i < 4; ++i) {
        if (vals[i] != -100) {
            pos[o]              = 4 * t + i;
            out_lab[b * SS + o] = (float)vals[i];
            ++o;
        }
    }
#pragma unroll
    for (int i = 0; i < 4; ++i) {
        int s = 4 * t + i;
        if (s >= c) { out_lab[b * SS + s] = PADV; out_cos[b * SS + s] = PADV; }
    }
    __syncthreads();

    int2 d[4];
#pragma unroll
    for (int i = 0; i < 4; ++i) {
        int j = 4 * t + i;
        if (j < c) {
            int jn = (j + 1 == c) ? 0 : (j + 1);
            d[i].x = pos[j];
            d[i].y = pos[jn];
        } else {
            d[i].x = -1;
            d[i].y = -1;
        }
    }
    int4* dp = (int4*)(desc + (size_t)b * SS + 4 * t);
    dp[0] = make_int4(d[0].x, d[0].y, d[1].x, d[1].y);
    dp[1] = make_int4(d[2].x, d[2].y, d[3].x, d[3].y);
}

// One block per 8 consecutive ranks. The 9 needed vectors (slots 0..8) are
// staged to LDS via global_load_lds (each read from global exactly ONCE:
// 4.6 KB/rank vs 6 KB direct). Wave w then computes pairs 2w,2w+1 from LDS.
// Slot s position: slot0 = desc[j0].x, slot s = desc[j0+s-1].y (covers wrap
// and partial tail blocks; -1 => slot unstaged & corresponding pair invalid).
__global__ __launch_bounds__(256) void cos_kernel(const float* __restrict__ x,
                                                  const int2* __restrict__ desc,
                                                  float* __restrict__ out_cos) {
    int b    = blockIdx.y;
    int j0   = blockIdx.x * 8;
    int t    = threadIdx.x;
    int lane = t & 63, wid = t >> 6;

    __shared__ float buf[9 * 1024];   // 36 KB: 9 slots x 4 KB

    const int2* dbase = desc + (size_t)b * SS + j0;
    int4 d01 = *(const int4*)(dbase + 0);
    if (d01.x < 0) return;            // block-uniform: whole block beyond cnt
    int4 d23 = *(const int4*)(dbase + 2);
    int4 d45 = *(const int4*)(dbase + 4);
    int4 d67 = *(const int4*)(dbase + 6);

    // slot positions (wave-uniform scalars; no runtime-indexed array)
    int P0 = d01.x, P1 = d01.y, P2 = d01.w, P3 = d23.y, P4 = d23.w;
    int P5 = d45.y, P6 = d45.w, P7 = d67.y, P8 = d67.w;

    const float* xb = x + (size_t)b * SS * DD;

#define STAGE_SLOT(S, PS)                                                      \
    if ((PS) >= 0) {                                                           \
        const float* g = xb + (size_t)(PS) * DD + lane * 4;                    \
        _Pragma("unroll")                                                      \
        for (int q = 0; q < 4; ++q) {                                          \
            __builtin_amdgcn_global_load_lds((GV*)(g + q * 256),               \
                                             (LV*)(&buf[((S) * 4 + q) * 256]), \
                                             16, 0, 0);                        \
        }                                                                      \
    }

    if (wid == 0)      { STAGE_SLOT(0, P0) STAGE_SLOT(1, P1) }
    else if (wid == 1) { STAGE_SLOT(2, P2) STAGE_SLOT(3, P3) }
    else if (wid == 2) { STAGE_SLOT(4, P4) STAGE_SLOT(5, P5) }
    else               { STAGE_SLOT(6, P6) STAGE_SLOT(7, P7) STAGE_SLOT(8, P8) }
#undef STAGE_SLOT

    __syncthreads();                  // drains vmcnt (incl. global_load_lds)

    int vA, vB;
    if (wid == 0)      { vA = d01.x; vB = d01.z; }
    else if (wid == 1) { vA = d23.x; vB = d23.z; }
    else if (wid == 2) { vA = d45.x; vB = d45.z; }
    else               { vA = d67.x; vB = d67.z; }
    if (vA < 0) return;               // after barrier; no later barriers

    bool p1 = (vB >= 0);
    const float4* lf = (const float4*)buf;
    int sA = wid * 2;

    float4 A[4], B[4], C[4];
#pragma unroll
    for (int q = 0; q < 4; ++q) {
        A[q] = lf[(sA * 4 + q)       * 64 + lane];
        B[q] = lf[((sA + 1) * 4 + q) * 64 + lane];
        C[q] = lf[((sA + 2) * 4 + q) * 64 + lane];  // garbage if !p1 (unused)
    }

    float na = 0.f, nb = 0.f, nc = 0.f, dab = 0.f, dbc = 0.f;
#pragma unroll
    for (int q = 0; q < 4; ++q) {
        na  += A[q].x*A[q].x + A[q].y*A[q].y + A[q].z*A[q].z + A[q].w*A[q].w;
        nb  += B[q].x*B[q].x + B[q].y*B[q].y + B[q].z*B[q].z + B[q].w*B[q].w;
        nc  += C[q].x*C[q].x + C[q].y*C[q].y + C[q].z*C[q].z + C[q].w*C[q].w;
        dab += A[q].x*B[q].x + A[q].y*B[q].y + A[q].z*B[q].z + A[q].w*B[q].w;
        dbc += B[q].x*C[q].x + B[q].y*C[q].y + B[q].z*C[q].z + B[q].w*C[q].w;
    }
#pragma unroll
    for (int off = 32; off; off >>= 1) {
        na  += __shfl_xor(na,  off, 64);
        nb  += __shfl_xor(nb,  off, 64);
        nc  += __shfl_xor(nc,  off, 64);
        dab += __shfl_xor(dab, off, 64);
        dbc += __shfl_xor(dbc, off, 64);
    }

    if (lane == 0) {
        int j = j0 + sA;
        float r0 = dab / fmaxf(sqrtf(na) * sqrtf(nb), EPSV) / TEMP;
        float* op = out_cos + b * SS + j;
        if (p1) {
            float r1 = dbc / fmaxf(sqrtf(nb) * sqrtf(nc), EPSV) / TEMP;
            *(float2*)op = make_float2(r0, r1);
        } else {
            *op = r0;
        }
    }
}

extern "C" void kernel_launch(void* const* d_in, const int* in_sizes, int n_in,
                              void* d_out, int out_size, void* d_ws, size_t ws_size,
                              hipStream_t stream) {
    const float* seq    = (const float*)d_in[0];   // [B,S,D] f32
    const int*   labels = (const int*)d_in[1];     // [B,S] i32

    float* out_cos = (float*)d_out;                // [B,S]
    float* out_lab = (float*)d_out + BB * SS;      // [B,S] as floats

    int2* desc = (int2*)d_ws;                      // B*S int2 descriptors

    compact_kernel<<<BB, 1024, 0, stream>>>(labels, desc, out_cos, out_lab);

    dim3 grid(SS / 8, BB);                         // 1 block per 8 ranks
    cos_kernel<<<grid, 256, 0, stream>>>(seq, desc, out_cos);
}